// Round 8
// baseline (300.060 us; speedup 1.0000x reference)
//
#include <hip/hip_runtime.h>

typedef unsigned short u16;
typedef __attribute__((ext_vector_type(8))) short short8;
typedef __attribute__((ext_vector_type(4))) float f32x4;
typedef __attribute__((ext_vector_type(2))) float f32x2;

#define N_AGENTS 131072
#define HID 128
#define FUT 12
#define OBS 8

constexpr int PAIRS = 4;   // 32-agent pair-tiles per block -> 128 agents/block
#define NEG_K  (-1.4426950408889634f)   // -log2(e)
#define NEG_2K (-2.8853900817779268f)   // -2*log2(e)

__device__ __forceinline__ u16 f2bf(float f) {   // RNE (setup only)
    union { float f; unsigned int i; } v; v.f = f;
    unsigned int u = v.i;
    return (u16)((u + 0x7fffu + ((u >> 16) & 1u)) >> 16);
}
__device__ __forceinline__ float bexp2(float x) {
#if __has_builtin(__builtin_amdgcn_exp2f)
    return __builtin_amdgcn_exp2f(x);
#else
    float r; asm("v_exp_f32 %0, %1" : "=v"(r) : "v"(x)); return r;
#endif
}
__device__ __forceinline__ float brcp(float x) {
#if __has_builtin(__builtin_amdgcn_rcpf)
    return __builtin_amdgcn_rcpf(x);
#else
    float r; asm("v_rcp_f32 %0, %1" : "=v"(r) : "v"(x)); return r;
#endif
}
__device__ __forceinline__ unsigned cvtpk(float lo, float hi) {  // 2x f32 -> packed bf16 (RNE)
    unsigned r; asm("v_cvt_pk_bf16_f32 %0, %1, %2" : "=v"(r) : "v"(lo), "v"(hi)); return r;
}

__launch_bounds__(512, 2)
__global__ void lstm_dec_kernel(const float* __restrict__ obs,
                                const float* __restrict__ h0g,
                                const float* __restrict__ Wih,
                                const float* __restrict__ Whh,
                                const float* __restrict__ bih,
                                const float* __restrict__ bhh,
                                const float* __restrict__ Wout,
                                const float* __restrict__ bout,
                                float* __restrict__ dout)
{
    __shared__ short8 hb[2][32][17];     // rows 0-15: tile A, 16-31: tile B
    __shared__ float  xt[32][2];
    __shared__ float  ot[FUT][32][2];

    const int tid  = threadIdx.x;
    const int lane = tid & 63;
    const int wv   = tid >> 6;      // wave 0..7, owns hidden [16*wv, 16*wv+16)
    const int r    = lane & 15;
    const int kb   = lane >> 4;

    const float bout0 = bout[0];
    const float bout1 = bout[1];

    // gate scale folded into weights: i,f,o -> -K ; g -> -2K  (nt: 0=i,1=f,2=g,3=o)
    const float gsc[4] = {NEG_K, NEG_K, NEG_2K, NEG_K};

    float wihs0[4], wihs1[4];
    f32x4 accInit[4];                // scaled bias as MFMA C-in
#pragma unroll
    for (int nt = 0; nt < 4; ++nt) {
        int c = nt * HID + wv * 16 + r;
        float w0 = Wih[c * 2 + 0];
        float w1 = Wih[c * 2 + 1];
        float be = (bih[c] + bhh[c] + w0 * bout0 + w1 * bout1) * gsc[nt];
        wihs0[nt] = w0 * gsc[nt];
        wihs1[nt] = w1 * gsc[nt];
        accInit[nt] = f32x4{be, be, be, be};
    }
    const float bo = (r == 0) ? bout0 : ((r == 1) ? bout1 : 0.0f);
    const f32x4 oInit = {bo, bo, bo, bo};

    // W_eff = (W_hh + W_ih @ W_out) * gsc  fragments (bf16): 64 VGPR; outb: 16
    short8 bfrag[4][4];
    short8 outb[4];
#pragma unroll
    for (int kf = 0; kf < 4; ++kf) {
        const int k0 = kf * 32 + kb * 8;
        float wo0[8], wo1[8];
        short8 ob;
#pragma unroll
        for (int j = 0; j < 8; ++j) {
            wo0[j] = Wout[0 * HID + k0 + j];
            wo1[j] = Wout[1 * HID + k0 + j];
            float sel = (r == 0) ? wo0[j] : ((r == 1) ? wo1[j] : 0.0f);
            ob[j] = (short)f2bf(sel);
        }
        outb[kf] = ob;
#pragma unroll
        for (int nt = 0; nt < 4; ++nt) {
            int c = nt * HID + wv * 16 + r;
            float s0 = wihs0[nt], s1 = wihs1[nt];   // already scaled
            short8 tt;
#pragma unroll
            for (int j = 0; j < 8; ++j) {
                float f = Whh[(size_t)c * HID + k0 + j] * gsc[nt]
                        + s0 * wo0[j] + s1 * wo1[j];
                tt[j] = (short)f2bf(f);
            }
            bfrag[nt][kf] = tt;
        }
    }

// ---- macros ----
#define LOADF(a, rb, rowoff)                                         \
    _Pragma("unroll")                                                \
    for (int kf = 0; kf < 4; ++kf)                                   \
        a[kf] = hb[rb][(rowoff) + r][kf * 4 + kb];

#define GATES_ONE(acc, a)                                            \
    _Pragma("unroll")                                                \
    for (int nt = 0; nt < 4; ++nt)                                   \
        acc[nt] = __builtin_amdgcn_mfma_f32_16x16x32_bf16(           \
            a[0], bfrag[nt][0], accInit[nt], 0, 0, 0);               \
    _Pragma("unroll")                                                \
    for (int kf = 1; kf < 4; ++kf)                                   \
        _Pragma("unroll")                                            \
        for (int nt = 0; nt < 4; ++nt)                               \
            acc[nt] = __builtin_amdgcn_mfma_f32_16x16x32_bf16(       \
                a[kf], bfrag[nt][kf], acc[nt], 0, 0, 0);

#define OUT_ONE(whichwv, a, dst_expr, rowoff)                        \
    if (wv == (whichwv)) {                                           \
        f32x4 oacc = __builtin_amdgcn_mfma_f32_16x16x32_bf16(        \
            a[0], outb[0], oInit, 0, 0, 0);                          \
        _Pragma("unroll")                                            \
        for (int kf = 1; kf < 4; ++kf)                               \
            oacc = __builtin_amdgcn_mfma_f32_16x16x32_bf16(          \
                a[kf], outb[kf], oacc, 0, 0, 0);                     \
        if (r < 2) {                                                 \
            _Pragma("unroll")                                        \
            for (int q = 0; q < 4; ++q)                              \
                (dst_expr)[(rowoff) + kb * 4 + q][r] = oacc[q];      \
        }                                                            \
    }

// packed pair-cell within a tile (q pair), math identical to R7
#define CELLP(acc, cf, qa, qb, rowoff)                               \
    {                                                                \
        f32x2 Ei = {bexp2(acc[0][qa]), bexp2(acc[0][qb])};           \
        f32x2 Ef = {bexp2(acc[1][qa]), bexp2(acc[1][qb])};           \
        f32x2 Gg = {bexp2(acc[2][qa]), bexp2(acc[2][qb])};           \
        f32x2 Eo = {bexp2(acc[3][qa]), bexp2(acc[3][qb])};           \
        f32x2 c2 = {cf[qa], cf[qb]};                                 \
        f32x2 t1 = 1.0f + Ei;                                        \
        f32x2 t2 = 1.0f + Gg;                                        \
        f32x2 t3 = 1.0f + Ef;                                        \
        f32x2 t12 = t1 * t2;                                         \
        f32x2 num = t12 * c2 + t3 * (1.0f - Gg);                     \
        f32x2 den = t12 * t3;                                        \
        f32x2 R1 = {brcp(den.x), brcp(den.y)};                       \
        f32x2 cn = num * R1;                                         \
        cf[qa] = cn.x; cf[qb] = cn.y;                                \
        f32x2 ga = NEG_2K * cn;                                      \
        f32x2 Gc = {bexp2(ga.x), bexp2(ga.y)};                       \
        f32x2 u1 = (1.0f + Eo) * (1.0f + Gc);                        \
        f32x2 R2 = {brcp(u1.x), brcp(u1.y)};                         \
        f32x2 hv = (1.0f - Gc) * R2;                                 \
        unsigned pk = cvtpk(hv.x, hv.y);                             \
        hbase[((rowoff) + kb * 4 + qa) * 136 + hcol] = (u16)pk;      \
        hbase[((rowoff) + kb * 4 + qb) * 136 + hcol] = (u16)(pk >> 16); \
    }

#define ACTIV_ONE(acc, cf, wb, rowoff)                               \
    {                                                                \
        u16* hbase = (u16*)&hb[wb][0][0];                            \
        const int hcol = wv * 16 + r;                                \
        CELLP(acc, cf, 0, 1, rowoff)                                 \
        CELLP(acc, cf, 2, 3, rowoff)                                 \
    }

#define CORR(acc, ox0v, ox1v, rowoff)                                \
    _Pragma("unroll")                                                \
    for (int q = 0; q < 4; ++q) {                                    \
        float dx0 = ox0v[q] - xt[(rowoff) + kb * 4 + q][0];          \
        float dx1 = ox1v[q] - xt[(rowoff) + kb * 4 + q][1];          \
        _Pragma("unroll")                                            \
        for (int nt = 0; nt < 4; ++nt)                               \
            acc[nt][q] += dx0 * wihs0[nt] + dx1 * wihs1[nt];         \
    }

#pragma unroll 1
    for (int t = 0; t < PAIRS; ++t) {
        const int A0 = (blockIdx.x * PAIRS + t) * 32;

        // cooperative h0 preload -> hb[1] (bf16), 32 rows x 128 cols
        {
            int row = tid >> 4;            // 32 rows, 16 threads/row
            int c8  = (tid & 15) * 8;
            const float* hp = h0g + (size_t)(A0 + row) * HID + c8;
            f32x4 lo = *(const f32x4*)hp;
            f32x4 hi = *(const f32x4*)(hp + 4);
            short8 a;
            unsigned* ap = (unsigned*)&a;
            ap[0] = cvtpk(lo[0], lo[1]);
            ap[1] = cvtpk(lo[2], lo[3]);
            ap[2] = cvtpk(hi[0], hi[1]);
            ap[3] = cvtpk(hi[2], hi[3]);
            hb[1][row][tid & 15] = a;
        }
        // obs x0 prefetch (tile A: rows 0-15, tile B: rows 16-31)
        float oxA0[4], oxA1[4], oxB0[4], oxB1[4];
#pragma unroll
        for (int q = 0; q < 4; ++q) {
            const float* opA = obs + ((size_t)(OBS - 1) * N_AGENTS + A0 + kb * 4 + q) * 2;
            const float* opB = obs + ((size_t)(OBS - 1) * N_AGENTS + A0 + 16 + kb * 4 + q) * 2;
            oxA0[q] = opA[0]; oxA1[q] = opA[1];
            oxB0[q] = opB[0]; oxB1[q] = opB[1];
        }
        f32x4 cfA = {0.f, 0.f, 0.f, 0.f};
        f32x4 cfB = {0.f, 0.f, 0.f, 0.f};
        f32x4 accA[4], accB[4];
        __syncthreads();

        // ---- phase 0: GATES(A,0) + x~0(A) ----
        {
            short8 aA[4];
            LOADF(aA, 1, 0)
            GATES_ONE(accA, aA)
            OUT_ONE(0, aA, xt, 0)
        }
        __syncthreads();

        // ---- phase 1: GATES(B,0) + x~0(B) ; corr(A) + ACTIV(A,0) ----
        {
            short8 aB[4];
            LOADF(aB, 1, 16)
            GATES_ONE(accB, aB)
            OUT_ONE(1, aB, xt, 16)
            CORR(accA, oxA0, oxA1, 0)
            ACTIV_ONE(accA, cfA, 0, 0)
        }
        __syncthreads();

        // ---- steps 1..11: two anti-phase half-steps each ----
#pragma unroll 2
        for (int s = 1; s < FUT; ++s) {
            const int rp = (s - 1) & 1;   // read parity
            const int wp = s & 1;         // write parity
            { // phase 2s: GATES(A,s)+OUT(A,s) ; ACTIV(B,s-1)
                short8 aA[4];
                LOADF(aA, rp, 0)
                GATES_ONE(accA, aA)
                OUT_ONE(0, aA, ot[s - 1], 0)
                if (s == 1) { CORR(accB, oxB0, oxB1, 16) }
                ACTIV_ONE(accB, cfB, rp, 16)
            }
            __syncthreads();
            { // phase 2s+1: GATES(B,s)+OUT(B,s) ; ACTIV(A,s)
                short8 aB[4];
                LOADF(aB, rp, 16)
                GATES_ONE(accB, aB)
                OUT_ONE(1, aB, ot[s - 1], 16)
                ACTIV_ONE(accA, cfA, wp, 0)
            }
            __syncthreads();
        }

        // ---- phase 24: OUT(A,12) ; ACTIV(B,11) ----
        {
            short8 aA[4];
            LOADF(aA, 1, 0)
            OUT_ONE(0, aA, ot[FUT - 1], 0)
            ACTIV_ONE(accB, cfB, 1, 16)
        }
        __syncthreads();

        // ---- phase 25: OUT(B,12) ----
        {
            short8 aB[4];
            LOADF(aB, 1, 16)
            OUT_ONE(1, aB, ot[FUT - 1], 16)
        }
        __syncthreads();

        // ---- coalesced flush: 768 floats ----
        {
            const float* otf = &ot[0][0][0];
            int idx = tid;                      // 0..511
            dout[((size_t)(idx >> 6) * N_AGENTS + A0) * 2 + (idx & 63)] = otf[idx];
            idx = tid + 512;
            if (idx < FUT * 64)
                dout[((size_t)(idx >> 6) * N_AGENTS + A0) * 2 + (idx & 63)] = otf[idx];
        }
        // next ot write (phase 2 of next pair) is >=2 barriers away — safe
    }
#undef LOADF
#undef GATES_ONE
#undef OUT_ONE
#undef CELLP
#undef ACTIV_ONE
#undef CORR
}

extern "C" void kernel_launch(void* const* d_in, const int* in_sizes, int n_in,
                              void* d_out, int out_size, void* d_ws, size_t ws_size,
                              hipStream_t stream) {
    const float* obs  = (const float*)d_in[0];
    // d_in[1] (fut_traj_rel) is unused by the reference
    const float* h0   = (const float*)d_in[2];
    const float* Wih  = (const float*)d_in[3];
    const float* Whh  = (const float*)d_in[4];
    const float* bih  = (const float*)d_in[5];
    const float* bhh  = (const float*)d_in[6];
    const float* Wout = (const float*)d_in[7];
    const float* bo   = (const float*)d_in[8];
    float* out = (float*)d_out;

    dim3 grid(N_AGENTS / (PAIRS * 32));   // 1024 blocks of 512 threads
    lstm_dec_kernel<<<grid, 512, 0, stream>>>(obs, h0, Wih, Whh, bih, bhh, Wout, bo, out);
}